// Round 13
// baseline (466.852 us; speedup 1.0000x reference)
//
#include <hip/hip_runtime.h>
#include <cstddef>

#define D 128
#define CHUNK 1024
#define BM 64        // rows per layer block (4 waves; 2M x 2N wave grid)
#define LDSH 136     // short row stride for h/t/ys (272B, bank-safe)

typedef __attribute__((ext_vector_type(8))) short s16x8;
typedef __attribute__((ext_vector_type(8))) unsigned short u16x8;
typedef __attribute__((ext_vector_type(4))) float f32x4;
typedef __attribute__((ext_vector_type(2))) float f32x2;

__device__ __forceinline__ unsigned short f2bf(float f) {
  unsigned u = __builtin_bit_cast(unsigned, f);
  u += 0x7FFFu + ((u >> 16) & 1u);
  return (unsigned short)(u >> 16);
}
__device__ __forceinline__ float bf2f(unsigned short h) {
  unsigned u = ((unsigned)h) << 16;
  return __builtin_bit_cast(float, u);
}
__device__ __forceinline__ unsigned f32x4_to_fp8(float4 v) {
  int r = __builtin_amdgcn_cvt_pk_fp8_f32(v.x, v.y, 0, false);
  r = __builtin_amdgcn_cvt_pk_fp8_f32(v.z, v.w, r, true);
  return (unsigned)r;
}
__device__ __forceinline__ void fp8x4_to_f32(unsigned u, float* o) {
  f32x2 lo = __builtin_amdgcn_cvt_pk_f32_fp8((int)u, false);
  f32x2 hi = __builtin_amdgcn_cvt_pk_f32_fp8((int)u, true);
  o[0] = lo[0]; o[1] = lo[1]; o[2] = hi[0]; o[3] = hi[1];
}

// ---------------- CSR build (once per call) ----------------
__global__ __launch_bounds__(256) void hist_kernel(const int* __restrict__ ei,
                                                   int* __restrict__ deg, int E) {
  int e = blockIdx.x * 256 + threadIdx.x;
  if (e < E) atomicAdd(&deg[ei[E + e]], 1);
}

__global__ __launch_bounds__(256) void partial_kernel(const int* __restrict__ deg,
                                                      int* __restrict__ partial, int N) {
  __shared__ int s[256];
  int base = blockIdx.x * CHUNK;
  int sum = 0;
  for (int j = threadIdx.x; j < CHUNK; j += 256) {
    int idx = base + j;
    sum += (idx < N) ? deg[idx] : 0;
  }
  s[threadIdx.x] = sum;
  __syncthreads();
  for (int ofs = 128; ofs > 0; ofs >>= 1) {
    if (threadIdx.x < ofs) s[threadIdx.x] += s[threadIdx.x + ofs];
    __syncthreads();
  }
  if (threadIdx.x == 0) partial[blockIdx.x] = s[0];
}

__global__ __launch_bounds__(1024) void scanpart_kernel(int* partial, int nb) {
  __shared__ int s[1024];
  int tid = threadIdx.x;
  int v = (tid < nb) ? partial[tid] : 0;
  s[tid] = v;
  __syncthreads();
  for (int o = 1; o < 1024; o <<= 1) {
    int t = (tid >= o) ? s[tid - o] : 0;
    __syncthreads();
    s[tid] += t;
    __syncthreads();
  }
  if (tid < nb) partial[tid] = s[tid] - v;
}

__global__ __launch_bounds__(256) void chunkscan_kernel(const int* __restrict__ deg,
                                                        const int* __restrict__ partial,
                                                        int* __restrict__ off, int N) {
  __shared__ int ws[4];
  int base = blockIdx.x * CHUNK;
  int i0 = base + threadIdx.x * 4;
  int d[4];
  int s = 0;
#pragma unroll
  for (int k = 0; k < 4; ++k) {
    d[k] = (i0 + k < N) ? deg[i0 + k] : 0;
    s += d[k];
  }
  int lane = threadIdx.x & 63;
  int incl = s;
  for (int o = 1; o < 64; o <<= 1) {
    int v = __shfl_up(incl, o, 64);
    if (lane >= o) incl += v;
  }
  int wave = threadIdx.x >> 6;
  if (lane == 63) ws[wave] = incl;
  __syncthreads();
  int wofs = 0;
  for (int w = 0; w < wave; ++w) wofs += ws[w];
  int run = partial[blockIdx.x] + wofs + (incl - s);
#pragma unroll
  for (int k = 0; k < 4; ++k) {
    int idx = i0 + k;
    if (idx < N) {
      off[idx] = run;
      run += d[k];
      if (idx == N - 1) off[N] = run;
    }
  }
}

// scatter + fp8 convert fused: half-wave per edge, ea read is sequential
__global__ __launch_bounds__(256) void scatter_conv_kernel(
    const int* __restrict__ ei, const float* __restrict__ ea,
    const int* __restrict__ off, int* __restrict__ cursor,
    int* __restrict__ sperm, unsigned char* __restrict__ eap, int E) {
  int t = blockIdx.x * 256 + threadIdx.x;
  int lane = t & 31;
  int e = t >> 5;
  if (e >= E) return;
  int p = 0;
  if (lane == 0) {
    int dnode = ei[E + e];
    p = off[dnode] + atomicAdd(&cursor[dnode], 1);
    sperm[p] = ei[e];
  }
  p = __shfl(p, 0, 32);
  float4 v = *reinterpret_cast<const float4*>(ea + (size_t)e * D + lane * 4);
  reinterpret_cast<unsigned*>(eap)[(size_t)p * 32 + lane] = f32x4_to_fp8(v);
}

// one-time: bf16 shadow of x_in
__global__ __launch_bounds__(256) void conv_x_kernel(const float* __restrict__ x,
                                                     unsigned short* __restrict__ xbf,
                                                     long long n8) {
  long long t = (long long)blockIdx.x * 256 + threadIdx.x;
  if (t >= n8) return;
  float4 v0 = reinterpret_cast<const float4*>(x)[t * 2];
  float4 v1 = reinterpret_cast<const float4*>(x)[t * 2 + 1];
  ushort4 o0, o1;
  o0.x = f2bf(v0.x); o0.y = f2bf(v0.y); o0.z = f2bf(v0.z); o0.w = f2bf(v0.w);
  o1.x = f2bf(v1.x); o1.y = f2bf(v1.y); o1.z = f2bf(v1.z); o1.w = f2bf(v1.w);
  reinterpret_cast<ushort4*>(xbf)[t * 2] = o0;
  reinterpret_cast<ushort4*>(xbf)[t * 2 + 1] = o1;
}

// ---------------- one-time: pack weights (B-frag bf16) + fold BN params ----------------
__global__ void pack_w_kernel(const float* __restrict__ W1, const float* __restrict__ W2,
                              const float* __restrict__ gamma, const float* __restrict__ beta,
                              const float* __restrict__ rmean, const float* __restrict__ rvar,
                              unsigned short* __restrict__ pk,
                              float* __restrict__ bnsc, float* __restrict__ bnbb) {
  int c = blockIdx.x;
  const float* Ws[2] = {W1 + (size_t)c * D * D, W2 + (size_t)c * D * D};
  unsigned short* base = pk + (size_t)c * 2 * D * D;
  if (threadIdx.x < D) {
    int col = threadIdx.x;
    float sc = gamma[(size_t)c * D + col] * rsqrtf(rvar[(size_t)c * D + col] + 1e-5f);
    bnsc[(size_t)c * D + col] = sc;
    bnbb[(size_t)c * D + col] = beta[(size_t)c * D + col] - rmean[(size_t)c * D + col] * sc;
  }
  for (int t = threadIdx.x; t < 2048; t += blockDim.x) {
    int ct = t >> 8, ks = (t >> 6) & 3, l = t & 63;
    int col = ct * 16 + (l & 15);
    int krow = ks * 32 + ((l >> 4) & 3) * 8;
    for (int w = 0; w < 2; ++w) {
      unsigned short* dst = base + (size_t)w * D * D;
      const float* W = Ws[w];
      for (int i = 0; i < 8; ++i)
        dst[(size_t)t * 8 + i] = f2bf(W[(size_t)(krow + i) * D + col]);
    }
  }
}

// ---------------- fused per-layer: bf16-state gather + bf16 MFMA MLP + epilogue ----------------
__global__ __launch_bounds__(256, 6) void layer_kernel(
    const unsigned short* __restrict__ xbf,
    const unsigned char* __restrict__ eap,
    const int* __restrict__ off, const int* __restrict__ sperm,
    const float* __restrict__ epsp,
    const unsigned short* __restrict__ wpk,   // w1|w2 (bf16, B-frag order)
    const float* __restrict__ b1, const float* __restrict__ b2,
    const float* __restrict__ mask,
    const float* __restrict__ bnsc, const float* __restrict__ bnbb,
    const float* __restrict__ x_in, float* __restrict__ out,
    unsigned short* __restrict__ xbf_out,
    int N, int is_last) {
  __shared__ __align__(16) unsigned short smem[BM * LDSH];  // 17408 B (h/T/Y aliased)
  unsigned short* h_s = smem;
  unsigned short* t_s = smem;
  unsigned short* y_s = smem;

  const int tid = threadIdx.x;
  const int r0 = blockIdx.x * BM;
  const float one_eps = 1.0f + epsp[0];

  // ---- phase 1: gather-aggregate (quarter-wave per row, 6-deep batched loads) ----
  {
    const int qw = tid >> 4;        // 0..15
    const int l16 = tid & 15;       // 8 elems per lane
    // prefetch all 4 rows' CSR ranges upfront (independent loads, one latency)
    int begs[4], ends[4];
#pragma unroll
    for (int it = 0; it < 4; ++it) {
      int gr = r0 + it * 16 + qw;
      int g = min(gr, N - 1);
      begs[it] = off[g];
      ends[it] = off[g + 1];
    }
#pragma unroll
    for (int it = 0; it < 4; ++it) {
      int row = it * 16 + qw;
      int gr = r0 + row;
      unsigned short* ph = h_s + row * LDSH + l16 * 8;
      if (gr >= N) {
        u16x8 z = {0, 0, 0, 0, 0, 0, 0, 0};
        *reinterpret_cast<u16x8*>(ph) = z;
        continue;
      }
      int beg = begs[it], end = ends[it];
      float acc[8] = {0.f, 0.f, 0.f, 0.f, 0.f, 0.f, 0.f, 0.f};
      for (int i = beg; i < end; i += 6) {
        int n = end - i;
        int idx[6], sidx[6];
#pragma unroll
        for (int k = 0; k < 6; ++k) idx[k] = (k < n) ? i + k : i;
#pragma unroll
        for (int k = 0; k < 6; ++k) sidx[k] = sperm[idx[k]];
        u16x8 xv[6];
        uint2 eu[6];
#pragma unroll
        for (int k = 0; k < 6; ++k) {
          xv[k] = *reinterpret_cast<const u16x8*>(xbf + (size_t)sidx[k] * D + l16 * 8);
          eu[k] = *reinterpret_cast<const uint2*>(eap + (size_t)idx[k] * D + l16 * 8);
        }
#pragma unroll
        for (int k = 0; k < 6; ++k) {
          if (k == 0 || k < n) {
            float ev[8];
            fp8x4_to_f32(eu[k].x, ev);
            fp8x4_to_f32(eu[k].y, ev + 4);
#pragma unroll
            for (int q = 0; q < 8; ++q)
              acc[q] += fmaxf(bf2f((unsigned short)xv[k][q]) + ev[q], 0.f);
          }
        }
      }
      u16x8 xo = *reinterpret_cast<const u16x8*>(xbf + (size_t)gr * D + l16 * 8);
      u16x8 hi8;
#pragma unroll
      for (int q = 0; q < 8; ++q)
        hi8[q] = f2bf(fmaf(one_eps, bf2f((unsigned short)xo[q]), acc[q]));
      *reinterpret_cast<u16x8*>(ph) = hi8;
    }
  }
  __syncthreads();  // barrier 1: h complete

  const int l = tid & 63;
  const int wave = tid >> 6;
  const int wm = wave >> 1;   // row half (32 rows)
  const int wn = wave & 1;    // col half (64 cols)
  const int cl = l & 15;
  const int kq = l >> 4;      // 0..3

  // ---- GEMM1: T = relu(h @ W1 + b1), pure bf16, regs-first ----
  f32x4 acc1[2][4];
  {
    s16x8 a[2][4];
#pragma unroll
    for (int rt = 0; rt < 2; ++rt) {
      int row = wm * 32 + rt * 16 + cl;
#pragma unroll
      for (int ks = 0; ks < 4; ++ks)
        a[rt][ks] = *reinterpret_cast<const s16x8*>(h_s + row * LDSH + ks * 32 + kq * 8);
    }
    const s16x8* w1 = reinterpret_cast<const s16x8*>(wpk);
#pragma unroll
    for (int ct = 0; ct < 4; ++ct) {
      int gct = wn * 4 + ct;
      f32x4 a0 = {0.f, 0.f, 0.f, 0.f};
      f32x4 a1 = {0.f, 0.f, 0.f, 0.f};
#pragma unroll
      for (int ks = 0; ks < 4; ++ks) {
        s16x8 bh = w1[(gct * 4 + ks) * 64 + l];
        a0 = __builtin_amdgcn_mfma_f32_16x16x32_bf16(a[0][ks], bh, a0, 0, 0, 0);
        a1 = __builtin_amdgcn_mfma_f32_16x16x32_bf16(a[1][ks], bh, a1, 0, 0, 0);
      }
      acc1[0][ct] = a0;
      acc1[1][ct] = a1;
    }
  }
  __syncthreads();  // barrier 2: all h reads retired -> region reusable as T

#pragma unroll
  for (int ct = 0; ct < 4; ++ct) {
    int gct = wn * 4 + ct;
    float bv = b1[gct * 16 + cl];
#pragma unroll
    for (int i = 0; i < 4; ++i) {
      t_s[(wm * 32 + kq * 4 + i) * LDSH + gct * 16 + cl] = f2bf(fmaxf(acc1[0][ct][i] + bv, 0.f));
      t_s[(wm * 32 + 16 + kq * 4 + i) * LDSH + gct * 16 + cl] = f2bf(fmaxf(acc1[1][ct][i] + bv, 0.f));
    }
  }
  __syncthreads();  // barrier 3: T complete

  // ---- GEMM2: Y = T @ W2, pure bf16, regs-first ----
  f32x4 acc2[2][4];
  {
    s16x8 a[2][4];
#pragma unroll
    for (int rt = 0; rt < 2; ++rt) {
      int row = wm * 32 + rt * 16 + cl;
#pragma unroll
      for (int ks = 0; ks < 4; ++ks)
        a[rt][ks] = *reinterpret_cast<const s16x8*>(t_s + row * LDSH + ks * 32 + kq * 8);
    }
    const s16x8* w2 = reinterpret_cast<const s16x8*>(wpk + D * D);
#pragma unroll
    for (int ct = 0; ct < 4; ++ct) {
      int gct = wn * 4 + ct;
      f32x4 a0 = {0.f, 0.f, 0.f, 0.f};
      f32x4 a1 = {0.f, 0.f, 0.f, 0.f};
#pragma unroll
      for (int ks = 0; ks < 4; ++ks) {
        s16x8 bh = w2[(gct * 4 + ks) * 64 + l];
        a0 = __builtin_amdgcn_mfma_f32_16x16x32_bf16(a[0][ks], bh, a0, 0, 0, 0);
        a1 = __builtin_amdgcn_mfma_f32_16x16x32_bf16(a[1][ks], bh, a1, 0, 0, 0);
      }
      acc2[0][ct] = a0;
      acc2[1][ct] = a1;
    }
  }
  __syncthreads();  // barrier 4: all T reads retired -> region reusable as Y

#pragma unroll
  for (int ct = 0; ct < 4; ++ct) {
    int gct = wn * 4 + ct;
#pragma unroll
    for (int i = 0; i < 4; ++i) {
      y_s[(wm * 32 + kq * 4 + i) * LDSH + gct * 16 + cl] = f2bf(acc2[0][ct][i]);
      y_s[(wm * 32 + 16 + kq * 4 + i) * LDSH + gct * 16 + cl] = f2bf(acc2[1][ct][i]);
    }
  }
  __syncthreads();  // barrier 5: Y complete

  // ---- epilogue: v = mask*(Y+b2) + x ; folded BN ; last: relu+outer residual (fp32 out)
  //      else: bf16 xbf_out only ----
  for (int j = tid; j < BM * 16; j += 256) {
    int row = j >> 4, c8 = j & 15;
    int gr = r0 + row;
    if (gr >= N) continue;
    u16x8 yb = *reinterpret_cast<const u16x8*>(y_s + row * LDSH + c8 * 8);
    u16x8 xr = *reinterpret_cast<const u16x8*>(xbf + (size_t)gr * D + c8 * 8);
    float mk = mask[gr];
    const float* b2p = b2 + c8 * 8;
    const float* scp = bnsc + c8 * 8;
    const float* bbp = bnbb + c8 * 8;
    float4 b20 = *reinterpret_cast<const float4*>(b2p);
    float4 b21 = *reinterpret_cast<const float4*>(b2p + 4);
    float4 sc0 = *reinterpret_cast<const float4*>(scp);
    float4 sc1 = *reinterpret_cast<const float4*>(scp + 4);
    float4 bb0 = *reinterpret_cast<const float4*>(bbp);
    float4 bb1 = *reinterpret_cast<const float4*>(bbp + 4);
    float b2a[8] = {b20.x, b20.y, b20.z, b20.w, b21.x, b21.y, b21.z, b21.w};
    float sca[8] = {sc0.x, sc0.y, sc0.z, sc0.w, sc1.x, sc1.y, sc1.z, sc1.w};
    float bba[8] = {bb0.x, bb0.y, bb0.z, bb0.w, bb1.x, bb1.y, bb1.z, bb1.w};
    float vo[8];
#pragma unroll
    for (int q = 0; q < 8; ++q) {
      float v = fmaf(mk, bf2f((unsigned short)yb[q]) + b2a[q], bf2f((unsigned short)xr[q]));
      vo[q] = fmaf(v, sca[q], bba[q]);
    }
    if (is_last) {
      const float* xip = x_in + (size_t)gr * D + c8 * 8;
      float4 xi0 = *reinterpret_cast<const float4*>(xip);
      float4 xi1 = *reinterpret_cast<const float4*>(xip + 4);
      float xi[8] = {xi0.x, xi0.y, xi0.z, xi0.w, xi1.x, xi1.y, xi1.z, xi1.w};
#pragma unroll
      for (int q = 0; q < 8; ++q) vo[q] = xi[q] + fmaxf(vo[q], 0.f);
      float4 w0 = make_float4(vo[0], vo[1], vo[2], vo[3]);
      float4 w1 = make_float4(vo[4], vo[5], vo[6], vo[7]);
      float* op = out + (size_t)gr * D + c8 * 8;
      *reinterpret_cast<float4*>(op) = w0;
      *reinterpret_cast<float4*>(op + 4) = w1;
    } else {
      u16x8 o;
#pragma unroll
      for (int q = 0; q < 8; ++q) o[q] = f2bf(vo[q]);
      *reinterpret_cast<u16x8*>(xbf_out + (size_t)gr * D + c8 * 8) = o;
    }
  }
}

static inline char* align_up(char* p, size_t a) {
  return (char*)(((size_t)p + a - 1) & ~(a - 1));
}

extern "C" void kernel_launch(void* const* d_in, const int* in_sizes, int n_in,
                              void* d_out, int out_size, void* d_ws, size_t ws_size,
                              hipStream_t stream) {
  const float* x_in  = (const float*)d_in[0];
  const int*   ei    = (const int*)d_in[1];
  const float* ea    = (const float*)d_in[2];
  const float* masks = (const float*)d_in[3];
  const float* W1    = (const float*)d_in[4];
  const float* b1    = (const float*)d_in[5];
  const float* W2    = (const float*)d_in[6];
  const float* b2    = (const float*)d_in[7];
  const float* eps   = (const float*)d_in[8];
  const float* gamma = (const float*)d_in[9];
  const float* beta  = (const float*)d_in[10];
  const float* rmean = (const float*)d_in[11];
  const float* rvar  = (const float*)d_in[12];
  const int N = in_sizes[0] / D;
  const int E = in_sizes[1] / 2;
  const int C = in_sizes[8];
  const int nb = (N + CHUNK - 1) / CHUNK;

  // workspace layout
  char* w = (char*)d_ws;
  int* deg     = (int*)w;    w += (size_t)N * sizeof(int);
  int* off     = (int*)w;    w += (size_t)(N + 1) * sizeof(int);
  int* cursor  = (int*)w;    w += (size_t)N * sizeof(int);
  int* partial = (int*)w;    w += (size_t)(nb + 1) * sizeof(int);
  int* sperm   = (int*)w;    w += (size_t)E * sizeof(int);
  w = align_up(w, 128);
  unsigned short* xbfA = (unsigned short*)w;  w += (size_t)N * D * sizeof(unsigned short);
  unsigned short* xbfB = (unsigned short*)w;  w += (size_t)N * D * sizeof(unsigned short);
  unsigned short* wpk  = (unsigned short*)w;  w += (size_t)C * 2 * D * D * sizeof(unsigned short);
  float* bnsc = (float*)w;   w += (size_t)C * D * sizeof(float);
  float* bnbb = (float*)w;   w += (size_t)C * D * sizeof(float);
  w = align_up(w, 128);
  unsigned char* eap = (unsigned char*)w;     // E * 128 bytes (fp8 e4m3)

  // ---- one-time: CSR + permuted fp8 edge_attr + packed weights/BN + bf16 x_in ----
  hipMemsetAsync(deg, 0, (size_t)N * sizeof(int), stream);
  hipMemsetAsync(cursor, 0, (size_t)N * sizeof(int), stream);
  hist_kernel<<<(E + 255) / 256, 256, 0, stream>>>(ei, deg, E);
  partial_kernel<<<nb, 256, 0, stream>>>(deg, partial, N);
  scanpart_kernel<<<1, 1024, 0, stream>>>(partial, nb);
  chunkscan_kernel<<<nb, 256, 0, stream>>>(deg, partial, off, N);
  scatter_conv_kernel<<<(E + 7) / 8, 256, 0, stream>>>(ei, ea, off, cursor, sperm, eap, E);
  pack_w_kernel<<<C, 256, 0, stream>>>(W1, W2, gamma, beta, rmean, rvar, wpk, bnsc, bnbb);
  long long n8 = (long long)N * D / 8;
  conv_x_kernel<<<(int)((n8 + 255) / 256), 256, 0, stream>>>(x_in, xbfA, n8);

  const int blocks = (N + BM - 1) / BM;
  const unsigned short* xbf_cur = xbfA;
  for (int c = 0; c < C; ++c) {
    unsigned short* xbf_next = (xbf_cur == xbfA) ? xbfB : xbfA;
    layer_kernel<<<blocks, 256, 0, stream>>>(
        xbf_cur, eap, off, sperm, eps + c,
        wpk + (size_t)c * 2 * D * D,
        b1 + (size_t)c * D, b2 + (size_t)c * D,
        masks + (size_t)c * N,
        bnsc + (size_t)c * D, bnbb + (size_t)c * D,
        x_in, (float*)d_out, xbf_next, N, (c == C - 1) ? 1 : 0);
    xbf_cur = xbf_next;
  }
}

// Round 14
// 430.911 us; speedup vs baseline: 1.0834x; 1.0834x over previous
//
#include <hip/hip_runtime.h>
#include <cstddef>

#define D 128
#define CHUNK 1024
#define BM 64        // rows per layer block (4 waves; 2M x 2N wave grid)
#define LDSH 136     // short row stride for h/t/ys (272B, bank-safe)

typedef __attribute__((ext_vector_type(8))) short s16x8;
typedef __attribute__((ext_vector_type(8))) unsigned short u16x8;
typedef __attribute__((ext_vector_type(4))) float f32x4;
typedef __attribute__((ext_vector_type(2))) float f32x2;

__device__ __forceinline__ unsigned short f2bf(float f) {
  unsigned u = __builtin_bit_cast(unsigned, f);
  u += 0x7FFFu + ((u >> 16) & 1u);
  return (unsigned short)(u >> 16);
}
__device__ __forceinline__ float bf2f(unsigned short h) {
  unsigned u = ((unsigned)h) << 16;
  return __builtin_bit_cast(float, u);
}
__device__ __forceinline__ unsigned f32x4_to_fp8(float4 v) {
  int r = __builtin_amdgcn_cvt_pk_fp8_f32(v.x, v.y, 0, false);
  r = __builtin_amdgcn_cvt_pk_fp8_f32(v.z, v.w, r, true);
  return (unsigned)r;
}
__device__ __forceinline__ void fp8x4_to_f32(unsigned u, float* o) {
  f32x2 lo = __builtin_amdgcn_cvt_pk_f32_fp8((int)u, false);
  f32x2 hi = __builtin_amdgcn_cvt_pk_f32_fp8((int)u, true);
  o[0] = lo[0]; o[1] = lo[1]; o[2] = hi[0]; o[3] = hi[1];
}

// ---------------- fused one-time prep: hist | pack_w+BN-fold | conv_x ----------------
// grid = nbh + C + nbx blocks, role selected by blockIdx.x range
__global__ __launch_bounds__(256) void prep_kernel(
    const int* __restrict__ ei, int E, int nbh,
    int* __restrict__ deg,
    const float* __restrict__ W1, const float* __restrict__ W2,
    const float* __restrict__ gamma, const float* __restrict__ beta,
    const float* __restrict__ rmean, const float* __restrict__ rvar,
    unsigned short* __restrict__ wpk,
    float* __restrict__ bnsc, float* __restrict__ bnbb, int C,
    const float* __restrict__ x_in, unsigned short* __restrict__ xbf, long long n8) {
  int b = blockIdx.x;
  if (b < nbh) {
    // ---- histogram of dst degrees ----
    int e = b * 256 + threadIdx.x;
    if (e < E) atomicAdd(&deg[ei[E + e]], 1);
    return;
  }
  b -= nbh;
  if (b < C) {
    // ---- pack weights (B-frag bf16) + fold BN ----
    int c = b;
    const float* Ws[2] = {W1 + (size_t)c * D * D, W2 + (size_t)c * D * D};
    unsigned short* base = wpk + (size_t)c * 2 * D * D;
    if (threadIdx.x < D) {
      int col = threadIdx.x;
      float sc = gamma[(size_t)c * D + col] * rsqrtf(rvar[(size_t)c * D + col] + 1e-5f);
      bnsc[(size_t)c * D + col] = sc;
      bnbb[(size_t)c * D + col] = beta[(size_t)c * D + col] - rmean[(size_t)c * D + col] * sc;
    }
    for (int t = threadIdx.x; t < 2048; t += blockDim.x) {
      int ct = t >> 8, ks = (t >> 6) & 3, l = t & 63;
      int col = ct * 16 + (l & 15);
      int krow = ks * 32 + ((l >> 4) & 3) * 8;
      for (int w = 0; w < 2; ++w) {
        unsigned short* dst = base + (size_t)w * D * D;
        const float* W = Ws[w];
        for (int i = 0; i < 8; ++i)
          dst[(size_t)t * 8 + i] = f2bf(W[(size_t)(krow + i) * D + col]);
      }
    }
    return;
  }
  b -= C;
  // ---- bf16 shadow of x_in ----
  long long t = (long long)b * 256 + threadIdx.x;
  if (t >= n8) return;
  float4 v0 = reinterpret_cast<const float4*>(x_in)[t * 2];
  float4 v1 = reinterpret_cast<const float4*>(x_in)[t * 2 + 1];
  ushort4 o0, o1;
  o0.x = f2bf(v0.x); o0.y = f2bf(v0.y); o0.z = f2bf(v0.z); o0.w = f2bf(v0.w);
  o1.x = f2bf(v1.x); o1.y = f2bf(v1.y); o1.z = f2bf(v1.z); o1.w = f2bf(v1.w);
  reinterpret_cast<ushort4*>(xbf)[t * 2] = o0;
  reinterpret_cast<ushort4*>(xbf)[t * 2 + 1] = o1;
}

// ---------------- CSR scans (once per call) ----------------
__global__ __launch_bounds__(256) void partial_kernel(const int* __restrict__ deg,
                                                      int* __restrict__ partial, int N) {
  __shared__ int s[256];
  int base = blockIdx.x * CHUNK;
  int sum = 0;
  for (int j = threadIdx.x; j < CHUNK; j += 256) {
    int idx = base + j;
    sum += (idx < N) ? deg[idx] : 0;
  }
  s[threadIdx.x] = sum;
  __syncthreads();
  for (int ofs = 128; ofs > 0; ofs >>= 1) {
    if (threadIdx.x < ofs) s[threadIdx.x] += s[threadIdx.x + ofs];
    __syncthreads();
  }
  if (threadIdx.x == 0) partial[blockIdx.x] = s[0];
}

__global__ __launch_bounds__(1024) void scanpart_kernel(int* partial, int nb) {
  __shared__ int s[1024];
  int tid = threadIdx.x;
  int v = (tid < nb) ? partial[tid] : 0;
  s[tid] = v;
  __syncthreads();
  for (int o = 1; o < 1024; o <<= 1) {
    int t = (tid >= o) ? s[tid - o] : 0;
    __syncthreads();
    s[tid] += t;
    __syncthreads();
  }
  if (tid < nb) partial[tid] = s[tid] - v;
}

__global__ __launch_bounds__(256) void chunkscan_kernel(const int* __restrict__ deg,
                                                        const int* __restrict__ partial,
                                                        int* __restrict__ off, int N) {
  __shared__ int ws[4];
  int base = blockIdx.x * CHUNK;
  int i0 = base + threadIdx.x * 4;
  int d[4];
  int s = 0;
#pragma unroll
  for (int k = 0; k < 4; ++k) {
    d[k] = (i0 + k < N) ? deg[i0 + k] : 0;
    s += d[k];
  }
  int lane = threadIdx.x & 63;
  int incl = s;
  for (int o = 1; o < 64; o <<= 1) {
    int v = __shfl_up(incl, o, 64);
    if (lane >= o) incl += v;
  }
  int wave = threadIdx.x >> 6;
  if (lane == 63) ws[wave] = incl;
  __syncthreads();
  int wofs = 0;
  for (int w = 0; w < wave; ++w) wofs += ws[w];
  int run = partial[blockIdx.x] + wofs + (incl - s);
#pragma unroll
  for (int k = 0; k < 4; ++k) {
    int idx = i0 + k;
    if (idx < N) {
      off[idx] = run;
      run += d[k];
      if (idx == N - 1) off[N] = run;
    }
  }
}

// scatter + fp8 convert fused: half-wave per edge, ea read is sequential
__global__ __launch_bounds__(256) void scatter_conv_kernel(
    const int* __restrict__ ei, const float* __restrict__ ea,
    const int* __restrict__ off, int* __restrict__ cursor,
    int* __restrict__ sperm, unsigned char* __restrict__ eap, int E) {
  int t = blockIdx.x * 256 + threadIdx.x;
  int lane = t & 31;
  int e = t >> 5;
  if (e >= E) return;
  int p = 0;
  if (lane == 0) {
    int dnode = ei[E + e];
    p = off[dnode] + atomicAdd(&cursor[dnode], 1);
    sperm[p] = ei[e];
  }
  p = __shfl(p, 0, 32);
  float4 v = *reinterpret_cast<const float4*>(ea + (size_t)e * D + lane * 4);
  reinterpret_cast<unsigned*>(eap)[(size_t)p * 32 + lane] = f32x4_to_fp8(v);
}

// ---------------- fused per-layer: bf16-state gather + bf16 MFMA MLP + epilogue ----------------
__global__ __launch_bounds__(256, 5) void layer_kernel(
    const unsigned short* __restrict__ xbf,
    const unsigned char* __restrict__ eap,
    const int* __restrict__ off, const int* __restrict__ sperm,
    const float* __restrict__ epsp,
    const unsigned short* __restrict__ wpk,   // w1|w2 (bf16, B-frag order)
    const float* __restrict__ b1, const float* __restrict__ b2,
    const float* __restrict__ mask,
    const float* __restrict__ bnsc, const float* __restrict__ bnbb,
    const float* __restrict__ x_in, float* __restrict__ out,
    unsigned short* __restrict__ xbf_out,
    int N, int is_last) {
  __shared__ __align__(16) unsigned short smem[BM * LDSH];  // 17408 B (h/T/Y aliased)
  unsigned short* h_s = smem;
  unsigned short* t_s = smem;
  unsigned short* y_s = smem;

  const int tid = threadIdx.x;
  const int r0 = blockIdx.x * BM;
  const float one_eps = 1.0f + epsp[0];

  // ---- phase 1: gather-aggregate (quarter-wave per row, 8-deep batched loads) ----
  {
    const int qw = tid >> 4;        // 0..15
    const int l16 = tid & 15;       // 8 elems per lane
#pragma unroll
    for (int it = 0; it < 4; ++it) {
      int row = it * 16 + qw;
      int gr = r0 + row;
      unsigned short* ph = h_s + row * LDSH + l16 * 8;
      if (gr >= N) {
        u16x8 z = {0, 0, 0, 0, 0, 0, 0, 0};
        *reinterpret_cast<u16x8*>(ph) = z;
        continue;
      }
      int beg = off[gr], end = off[gr + 1];
      float acc[8] = {0.f, 0.f, 0.f, 0.f, 0.f, 0.f, 0.f, 0.f};
      for (int i = beg; i < end; i += 8) {
        int n = end - i;
        int idx[8], sidx[8];
#pragma unroll
        for (int k = 0; k < 8; ++k) idx[k] = (k < n) ? i + k : i;
#pragma unroll
        for (int k = 0; k < 8; ++k) sidx[k] = sperm[idx[k]];
        u16x8 xv[8];
        uint2 eu[8];
#pragma unroll
        for (int k = 0; k < 8; ++k) {
          xv[k] = *reinterpret_cast<const u16x8*>(xbf + (size_t)sidx[k] * D + l16 * 8);
          eu[k] = *reinterpret_cast<const uint2*>(eap + (size_t)idx[k] * D + l16 * 8);
        }
#pragma unroll
        for (int k = 0; k < 8; ++k) {
          if (k == 0 || k < n) {
            float ev[8];
            fp8x4_to_f32(eu[k].x, ev);
            fp8x4_to_f32(eu[k].y, ev + 4);
#pragma unroll
            for (int q = 0; q < 8; ++q)
              acc[q] += fmaxf(bf2f((unsigned short)xv[k][q]) + ev[q], 0.f);
          }
        }
      }
      u16x8 xo = *reinterpret_cast<const u16x8*>(xbf + (size_t)gr * D + l16 * 8);
      u16x8 hi8;
#pragma unroll
      for (int q = 0; q < 8; ++q)
        hi8[q] = f2bf(fmaf(one_eps, bf2f((unsigned short)xo[q]), acc[q]));
      *reinterpret_cast<u16x8*>(ph) = hi8;
    }
  }
  __syncthreads();  // barrier 1: h complete

  const int l = tid & 63;
  const int wave = tid >> 6;
  const int wm = wave >> 1;   // row half (32 rows)
  const int wn = wave & 1;    // col half (64 cols)
  const int cl = l & 15;
  const int kq = l >> 4;      // 0..3

  // ---- GEMM1: T = relu(h @ W1 + b1), pure bf16, regs-first ----
  f32x4 acc1[2][4];
  {
    s16x8 a[2][4];
#pragma unroll
    for (int rt = 0; rt < 2; ++rt) {
      int row = wm * 32 + rt * 16 + cl;
#pragma unroll
      for (int ks = 0; ks < 4; ++ks)
        a[rt][ks] = *reinterpret_cast<const s16x8*>(h_s + row * LDSH + ks * 32 + kq * 8);
    }
    const s16x8* w1 = reinterpret_cast<const s16x8*>(wpk);
#pragma unroll
    for (int ct = 0; ct < 4; ++ct) {
      int gct = wn * 4 + ct;
      f32x4 a0 = {0.f, 0.f, 0.f, 0.f};
      f32x4 a1 = {0.f, 0.f, 0.f, 0.f};
#pragma unroll
      for (int ks = 0; ks < 4; ++ks) {
        s16x8 bh = w1[(gct * 4 + ks) * 64 + l];
        a0 = __builtin_amdgcn_mfma_f32_16x16x32_bf16(a[0][ks], bh, a0, 0, 0, 0);
        a1 = __builtin_amdgcn_mfma_f32_16x16x32_bf16(a[1][ks], bh, a1, 0, 0, 0);
      }
      acc1[0][ct] = a0;
      acc1[1][ct] = a1;
    }
  }
  __syncthreads();  // barrier 2: all h reads retired -> region reusable as T

#pragma unroll
  for (int ct = 0; ct < 4; ++ct) {
    int gct = wn * 4 + ct;
    float bv = b1[gct * 16 + cl];
#pragma unroll
    for (int i = 0; i < 4; ++i) {
      t_s[(wm * 32 + kq * 4 + i) * LDSH + gct * 16 + cl] = f2bf(fmaxf(acc1[0][ct][i] + bv, 0.f));
      t_s[(wm * 32 + 16 + kq * 4 + i) * LDSH + gct * 16 + cl] = f2bf(fmaxf(acc1[1][ct][i] + bv, 0.f));
    }
  }
  __syncthreads();  // barrier 3: T complete

  // ---- GEMM2: Y = T @ W2, pure bf16, regs-first ----
  f32x4 acc2[2][4];
  {
    s16x8 a[2][4];
#pragma unroll
    for (int rt = 0; rt < 2; ++rt) {
      int row = wm * 32 + rt * 16 + cl;
#pragma unroll
      for (int ks = 0; ks < 4; ++ks)
        a[rt][ks] = *reinterpret_cast<const s16x8*>(t_s + row * LDSH + ks * 32 + kq * 8);
    }
    const s16x8* w2 = reinterpret_cast<const s16x8*>(wpk + D * D);
#pragma unroll
    for (int ct = 0; ct < 4; ++ct) {
      int gct = wn * 4 + ct;
      f32x4 a0 = {0.f, 0.f, 0.f, 0.f};
      f32x4 a1 = {0.f, 0.f, 0.f, 0.f};
#pragma unroll
      for (int ks = 0; ks < 4; ++ks) {
        s16x8 bh = w2[(gct * 4 + ks) * 64 + l];
        a0 = __builtin_amdgcn_mfma_f32_16x16x32_bf16(a[0][ks], bh, a0, 0, 0, 0);
        a1 = __builtin_amdgcn_mfma_f32_16x16x32_bf16(a[1][ks], bh, a1, 0, 0, 0);
      }
      acc2[0][ct] = a0;
      acc2[1][ct] = a1;
    }
  }
  __syncthreads();  // barrier 4: all T reads retired -> region reusable as Y

#pragma unroll
  for (int ct = 0; ct < 4; ++ct) {
    int gct = wn * 4 + ct;
#pragma unroll
    for (int i = 0; i < 4; ++i) {
      y_s[(wm * 32 + kq * 4 + i) * LDSH + gct * 16 + cl] = f2bf(acc2[0][ct][i]);
      y_s[(wm * 32 + 16 + kq * 4 + i) * LDSH + gct * 16 + cl] = f2bf(acc2[1][ct][i]);
    }
  }
  __syncthreads();  // barrier 5: Y complete

  // ---- epilogue: v = mask*(Y+b2) + x ; folded BN ; last: relu+outer residual (fp32 out)
  //      else: bf16 xbf_out only ----
  for (int j = tid; j < BM * 16; j += 256) {
    int row = j >> 4, c8 = j & 15;
    int gr = r0 + row;
    if (gr >= N) continue;
    u16x8 yb = *reinterpret_cast<const u16x8*>(y_s + row * LDSH + c8 * 8);
    u16x8 xr = *reinterpret_cast<const u16x8*>(xbf + (size_t)gr * D + c8 * 8);
    float mk = mask[gr];
    const float* b2p = b2 + c8 * 8;
    const float* scp = bnsc + c8 * 8;
    const float* bbp = bnbb + c8 * 8;
    float4 b20 = *reinterpret_cast<const float4*>(b2p);
    float4 b21 = *reinterpret_cast<const float4*>(b2p + 4);
    float4 sc0 = *reinterpret_cast<const float4*>(scp);
    float4 sc1 = *reinterpret_cast<const float4*>(scp + 4);
    float4 bb0 = *reinterpret_cast<const float4*>(bbp);
    float4 bb1 = *reinterpret_cast<const float4*>(bbp + 4);
    float b2a[8] = {b20.x, b20.y, b20.z, b20.w, b21.x, b21.y, b21.z, b21.w};
    float sca[8] = {sc0.x, sc0.y, sc0.z, sc0.w, sc1.x, sc1.y, sc1.z, sc1.w};
    float bba[8] = {bb0.x, bb0.y, bb0.z, bb0.w, bb1.x, bb1.y, bb1.z, bb1.w};
    float vo[8];
#pragma unroll
    for (int q = 0; q < 8; ++q) {
      float v = fmaf(mk, bf2f((unsigned short)yb[q]) + b2a[q], bf2f((unsigned short)xr[q]));
      vo[q] = fmaf(v, sca[q], bba[q]);
    }
    if (is_last) {
      const float* xip = x_in + (size_t)gr * D + c8 * 8;
      float4 xi0 = *reinterpret_cast<const float4*>(xip);
      float4 xi1 = *reinterpret_cast<const float4*>(xip + 4);
      float xi[8] = {xi0.x, xi0.y, xi0.z, xi0.w, xi1.x, xi1.y, xi1.z, xi1.w};
#pragma unroll
      for (int q = 0; q < 8; ++q) vo[q] = xi[q] + fmaxf(vo[q], 0.f);
      float4 w0 = make_float4(vo[0], vo[1], vo[2], vo[3]);
      float4 w1 = make_float4(vo[4], vo[5], vo[6], vo[7]);
      float* op = out + (size_t)gr * D + c8 * 8;
      *reinterpret_cast<float4*>(op) = w0;
      *reinterpret_cast<float4*>(op + 4) = w1;
    } else {
      u16x8 o;
#pragma unroll
      for (int q = 0; q < 8; ++q) o[q] = f2bf(vo[q]);
      *reinterpret_cast<u16x8*>(xbf_out + (size_t)gr * D + c8 * 8) = o;
    }
  }
}

static inline char* align_up(char* p, size_t a) {
  return (char*)(((size_t)p + a - 1) & ~(a - 1));
}

extern "C" void kernel_launch(void* const* d_in, const int* in_sizes, int n_in,
                              void* d_out, int out_size, void* d_ws, size_t ws_size,
                              hipStream_t stream) {
  const float* x_in  = (const float*)d_in[0];
  const int*   ei    = (const int*)d_in[1];
  const float* ea    = (const float*)d_in[2];
  const float* masks = (const float*)d_in[3];
  const float* W1    = (const float*)d_in[4];
  const float* b1    = (const float*)d_in[5];
  const float* W2    = (const float*)d_in[6];
  const float* b2    = (const float*)d_in[7];
  const float* eps   = (const float*)d_in[8];
  const float* gamma = (const float*)d_in[9];
  const float* beta  = (const float*)d_in[10];
  const float* rmean = (const float*)d_in[11];
  const float* rvar  = (const float*)d_in[12];
  const int N = in_sizes[0] / D;
  const int E = in_sizes[1] / 2;
  const int C = in_sizes[8];
  const int nb = (N + CHUNK - 1) / CHUNK;

  // workspace layout (deg and cursor adjacent -> single memset)
  char* w = (char*)d_ws;
  int* deg     = (int*)w;    w += (size_t)N * sizeof(int);
  int* cursor  = (int*)w;    w += (size_t)N * sizeof(int);
  int* off     = (int*)w;    w += (size_t)(N + 1) * sizeof(int);
  int* partial = (int*)w;    w += (size_t)(nb + 1) * sizeof(int);
  int* sperm   = (int*)w;    w += (size_t)E * sizeof(int);
  w = align_up(w, 128);
  unsigned short* xbfA = (unsigned short*)w;  w += (size_t)N * D * sizeof(unsigned short);
  unsigned short* xbfB = (unsigned short*)w;  w += (size_t)N * D * sizeof(unsigned short);
  unsigned short* wpk  = (unsigned short*)w;  w += (size_t)C * 2 * D * D * sizeof(unsigned short);
  float* bnsc = (float*)w;   w += (size_t)C * D * sizeof(float);
  float* bnbb = (float*)w;   w += (size_t)C * D * sizeof(float);
  w = align_up(w, 128);
  unsigned char* eap = (unsigned char*)w;     // E * 128 bytes (fp8 e4m3)

  // ---- one-time preprocessing: 6 launches total before the layer loop ----
  hipMemsetAsync(deg, 0, (size_t)2 * N * sizeof(int), stream);  // deg + cursor
  const int nbh = (E + 255) / 256;
  const long long n8 = (long long)N * D / 8;
  const int nbx = (int)((n8 + 255) / 256);
  prep_kernel<<<nbh + C + nbx, 256, 0, stream>>>(
      ei, E, nbh, deg,
      W1, W2, gamma, beta, rmean, rvar, wpk, bnsc, bnbb, C,
      x_in, xbfA, n8);
  partial_kernel<<<nb, 256, 0, stream>>>(deg, partial, N);
  scanpart_kernel<<<1, 1024, 0, stream>>>(partial, nb);
  chunkscan_kernel<<<nb, 256, 0, stream>>>(deg, partial, off, N);
  scatter_conv_kernel<<<(E + 7) / 8, 256, 0, stream>>>(ei, ea, off, cursor, sperm, eap, E);

  const int blocks = (N + BM - 1) / BM;
  const unsigned short* xbf_cur = xbfA;
  for (int c = 0; c < C; ++c) {
    unsigned short* xbf_next = (xbf_cur == xbfA) ? xbfB : xbfA;
    layer_kernel<<<blocks, 256, 0, stream>>>(
        xbf_cur, eap, off, sperm, eps + c,
        wpk + (size_t)c * 2 * D * D,
        b1 + (size_t)c * D, b2 + (size_t)c * D,
        masks + (size_t)c * N,
        bnsc + (size_t)c * D, bnbb + (size_t)c * D,
        x_in, (float*)d_out, xbf_next, N, (c == C - 1) ? 1 : 0);
    xbf_cur = xbf_next;
  }
}